// Round 17
// baseline (3998.129 us; speedup 1.0000x reference)
//
#include <hip/hip_runtime.h>

#define KLEN 1024
#define HOP 512
#define NW 511
#define NB 4
#define NC 16
#define NBINS 513
#define NSAMP 262144

__global__ __launch_bounds__(256) void dechirp_realpart_kernel(
    const float* __restrict__ x,
    const float* __restrict__ dlnf,
    float* __restrict__ out)            // float32 REAL PART of rfft
{
    __shared__ double wd[KLEN];
    __shared__ double rs[KLEN];
    __shared__ double cth[KLEN];

    const int tid = threadIdx.x;
    const int blin = blockIdx.x;            // ((b*NW + w)*NC + c)
    const int c = blin & (NC - 1);
    const int w = (blin >> 4) % NW;
    const int b = blin / (NC * NW);

    const double TWO_PI = 6.283185307179586476925287;

    for (int t = tid; t < KLEN; t += 256)
        cth[t] = cos(TWO_PI * (double)t / 1024.0);

    const float* xrow = x + (size_t)b * NSAMP + (size_t)w * HOP;
    for (int k = tid; k < KLEN; k += 256) {
        double hann = 0.5 * (1.0 - cos(TWO_PI * (double)k / 1024.0));
        wd[k] = (double)xrow[k] * hann;
    }

    const double beta = 2.0 * (double)dlnf[c];
    const bool small = fabs(beta) < 1e-8;
    const double bs = small ? 1e-8 : beta;
    const double e2b = exp(2.0 * bs);
    const double t_mid = small ? 0.0 : (log(1.0 + 0.5 * (e2b - 1.0)) / bs - 1.0);

    __syncthreads();

    // Faithful listing resample WITH jac (fp64)
    for (int j = tid; j < KLEN; j += 256) {
        double tau = 2.0 * (double)j / 1024.0 - 1.0;
        double ts, jac;
        if (small) {
            ts = tau;
            jac = 1.0;
        } else {
            ts = log(1.0 + (tau + 1.0) * 0.5 * (e2b - 1.0)) / bs - 1.0;
            jac = exp(-bs * (ts - t_mid));
        }
        double idxf = 512.0 * (ts + 1.0);
        int lo = (int)idxf;               // trunc toward zero, like astype(int32)
        lo = lo < 0 ? 0 : (lo > 1022 ? 1022 : lo);
        double frac = idxf - (double)lo;  // may exceed [0,1]: matches ref
        rs[j] = (wd[lo] * (1.0 - frac) + wd[lo + 1] * frac) * jac;
    }
    __syncthreads();

    // Real part of rfft: Re X_k = sum_n rs[n] * cos(2*pi*k*n/1024)
    size_t obase = (size_t)blin * NBINS;
    for (int k = tid; k < NBINS; k += 256) {
        double ar = 0.0;
        for (int n = 0; n < KLEN; ++n) {
            int t = (k * n) & (KLEN - 1);
            ar = fma(rs[n], cth[t], ar);
        }
        out[obase + k] = (float)ar;
    }
}

extern "C" void kernel_launch(void* const* d_in, const int* in_sizes, int n_in,
                              void* d_out, int out_size, void* d_ws, size_t ws_size,
                              hipStream_t stream) {
    const float* x = nullptr;
    const float* dlnf = nullptr;
    for (int i = 0; i < n_in; ++i) {
        if (in_sizes[i] == NB * NSAMP)      x = (const float*)d_in[i];
        else if (in_sizes[i] == NC)         dlnf = (const float*)d_in[i];
    }
    if (!x)    x    = (const float*)d_in[0];
    if (!dlnf) dlnf = (const float*)d_in[1];
    float* out = (float*)d_out;

    const int nblocks = NB * NW * NC;  // 32704
    dechirp_realpart_kernel<<<nblocks, 256, 0, stream>>>(x, dlnf, out);
}

// Round 18
// 353.177 us; speedup vs baseline: 11.3205x; 11.3205x over previous
//
#include <hip/hip_runtime.h>

#define KLEN 1024
#define HOP 512
#define NW 511
#define NB 4
#define NC 16
#define NBINS 513
#define NSAMP 262144

__global__ __launch_bounds__(256) void dechirp_fft_kernel(
    const float* __restrict__ x,
    const float* __restrict__ dlnf,
    float* __restrict__ out)            // float32 REAL PART of rfft
{
    __shared__ float wd[KLEN];
    __shared__ float re[KLEN], im[KLEN];
    __shared__ float twr[512], twi[512];

    const int tid = threadIdx.x;
    const int blin = blockIdx.x;            // ((b*NW + w)*NC + c)
    const int c = blin & (NC - 1);
    const int w = (blin >> 4) % NW;
    const int b = blin / (NC * NW);

    // Twiddles: exp(-2*pi*i*t/1024)
    for (int t = tid; t < 512; t += 256) {
        float s, cv;
        sincosf(-6.2831853071795864769f * (float)t * (1.0f / 1024.0f), &s, &cv);
        twr[t] = cv;
        twi[t] = s;
    }

    // Windowed row (f32, matches np float32 pipeline)
    const float* xrow = x + (size_t)b * NSAMP + (size_t)w * HOP;
    for (int k = tid; k < KLEN; k += 256) {
        float hann = 0.5f * (1.0f - cosf(6.2831853071795864769f * (float)k * (1.0f / 1024.0f)));
        wd[k] = xrow[k] * hann;
    }

    // Chirp parameters in fp64 (cheap, error-sensitive)
    const double beta = 2.0 * (double)dlnf[c];
    const bool small = fabs(beta) < 1e-8;
    const double bs = small ? 1e-8 : beta;
    const double e2b = exp(2.0 * bs);
    const double t_mid = small ? 0.0 : (log(1.0 + 0.5 * (e2b - 1.0)) / bs - 1.0);

    __syncthreads();

    // Resample into bit-reversed FFT positions; warp map fp64, value f32
    for (int j = tid; j < KLEN; j += 256) {
        double tau = 2.0 * (double)j / 1024.0 - 1.0;
        double ts, jac;
        if (small) {
            ts = tau;
            jac = 1.0;
        } else {
            ts = log(1.0 + (tau + 1.0) * 0.5 * (e2b - 1.0)) / bs - 1.0;
            jac = exp(-bs * (ts - t_mid));
        }
        double idxf = 512.0 * (ts + 1.0);
        int lo = (int)idxf;               // trunc toward zero, like astype(int32)
        lo = lo < 0 ? 0 : (lo > 1022 ? 1022 : lo);
        float frac = (float)(idxf - (double)lo);
        float v = (wd[lo] * (1.0f - frac) + wd[lo + 1] * frac) * (float)jac;
        int r = (int)(__brev((unsigned)j) >> 22);  // 10-bit reversal
        re[r] = v;
        im[r] = 0.0f;
    }
    __syncthreads();

    // In-place radix-2 DIT, 10 stages (bit-validated vs DFT in r2-r4)
    for (int len = 2; len <= KLEN; len <<= 1) {
        int half = len >> 1;
        int tmul = KLEN / len;
        for (int bf = tid; bf < 512; bf += 256) {
            int j = bf & (half - 1);
            int p1 = ((bf & ~(half - 1)) << 1) | j;
            int p2 = p1 + half;
            int ti = j * tmul;
            float wr = twr[ti], wi = twi[ti];
            float ar = re[p2], ai = im[p2];
            float vr = ar * wr - ai * wi;
            float vi = ar * wi + ai * wr;
            float ur = re[p1], ui = im[p1];
            re[p1] = ur + vr; im[p1] = ui + vi;
            re[p2] = ur - vr; im[p2] = ui - vi;
        }
        __syncthreads();
    }

    // Write the 513 real components, coalesced
    size_t obase = (size_t)blin * NBINS;
    out[obase + tid]       = re[tid];
    out[obase + tid + 256] = re[tid + 256];
    if (tid == 0)
        out[obase + 512]   = re[512];
}

extern "C" void kernel_launch(void* const* d_in, const int* in_sizes, int n_in,
                              void* d_out, int out_size, void* d_ws, size_t ws_size,
                              hipStream_t stream) {
    const float* x = nullptr;
    const float* dlnf = nullptr;
    for (int i = 0; i < n_in; ++i) {
        if (in_sizes[i] == NB * NSAMP)      x = (const float*)d_in[i];
        else if (in_sizes[i] == NC)         dlnf = (const float*)d_in[i];
    }
    if (!x)    x    = (const float*)d_in[0];
    if (!dlnf) dlnf = (const float*)d_in[1];
    float* out = (float*)d_out;

    const int nblocks = NB * NW * NC;  // 32704
    dechirp_fft_kernel<<<nblocks, 256, 0, stream>>>(x, dlnf, out);
}

// Round 19
// 190.510 us; speedup vs baseline: 20.9864x; 1.8538x over previous
//
#include <hip/hip_runtime.h>

#define KLEN 1024
#define HOP 512
#define NW 511
#define NB 4
#define NC 16
#define NBINS 513
#define NSAMP 262144

// d_ws layout: int lo[16*1024] | float frac[16*1024] | float jac[16*1024]
#define MAPN (NC * KLEN)

__global__ __launch_bounds__(256) void warpmap_kernel(
    const float* __restrict__ dlnf,
    int* __restrict__ lo_t, float* __restrict__ fr_t, float* __restrict__ ja_t)
{
    const int c = blockIdx.x;
    const double beta = 2.0 * (double)dlnf[c];
    const bool small = fabs(beta) < 1e-8;
    const double bs = small ? 1e-8 : beta;
    const double e2b = exp(2.0 * bs);
    const double t_mid = small ? 0.0 : (log(1.0 + 0.5 * (e2b - 1.0)) / bs - 1.0);

    for (int j = threadIdx.x; j < KLEN; j += 256) {
        double tau = 2.0 * (double)j / 1024.0 - 1.0;
        double ts, jac;
        if (small) {
            ts = tau;
            jac = 1.0;
        } else {
            ts = log(1.0 + (tau + 1.0) * 0.5 * (e2b - 1.0)) / bs - 1.0;
            jac = exp(-bs * (ts - t_mid));
        }
        double idxf = 512.0 * (ts + 1.0);
        int lo = (int)idxf;               // trunc toward zero, like astype(int32)
        lo = lo < 0 ? 0 : (lo > 1022 ? 1022 : lo);
        lo_t[c * KLEN + j] = lo;
        fr_t[c * KLEN + j] = (float)(idxf - (double)lo);
        ja_t[c * KLEN + j] = (float)jac;
    }
}

__global__ __launch_bounds__(256) void dechirp_fft2_kernel(
    const float* __restrict__ x,
    const int* __restrict__ lo_t, const float* __restrict__ fr_t,
    const float* __restrict__ ja_t,
    float* __restrict__ out)            // float32 REAL PART of rfft
{
    __shared__ float wd[KLEN];
    __shared__ float re[KLEN], im[KLEN];
    __shared__ float twr[512], twi[512];

    const int tid = threadIdx.x;
    const int blin = blockIdx.x;            // ((b*NW + w)*8 + q), q = chirp pair
    const int q = blin & 7;
    const int w = (blin >> 3) % NW;
    const int b = blin / (8 * NW);
    const int c0 = 2 * q, c1 = 2 * q + 1;

    // Twiddles exp(-2*pi*i*t/1024)
    for (int t = tid; t < 512; t += 256) {
        float s, cv;
        sincosf(-6.2831853071795864769f * (float)t * (1.0f / 1024.0f), &s, &cv);
        twr[t] = cv;
        twi[t] = s;
    }

    // Windowed frame (shared by both chirps)
    const float* xrow = x + (size_t)b * NSAMP + (size_t)w * HOP;
    for (int k = tid; k < KLEN; k += 256) {
        float hann = 0.5f * (1.0f - cosf(6.2831853071795864769f * (float)k * (1.0f / 1024.0f)));
        wd[k] = xrow[k] * hann;
    }
    __syncthreads();

    // Resample both chirps; pack z = f + i*g at bit-reversed positions
    const int* lo0 = lo_t + c0 * KLEN;  const float* fr0 = fr_t + c0 * KLEN;  const float* ja0 = ja_t + c0 * KLEN;
    const int* lo1 = lo_t + c1 * KLEN;  const float* fr1 = fr_t + c1 * KLEN;  const float* ja1 = ja_t + c1 * KLEN;
    for (int j = tid; j < KLEN; j += 256) {
        int   a0 = lo0[j];  float f0 = fr0[j];
        float vf = (wd[a0] * (1.0f - f0) + wd[a0 + 1] * f0) * ja0[j];
        int   a1 = lo1[j];  float f1 = fr1[j];
        float vg = (wd[a1] * (1.0f - f1) + wd[a1 + 1] * f1) * ja1[j];
        int r = (int)(__brev((unsigned)j) >> 22);  // 10-bit reversal
        re[r] = vf;
        im[r] = vg;
    }
    __syncthreads();

    // In-place radix-2 DIT, 10 stages
    for (int len = 2; len <= KLEN; len <<= 1) {
        int half = len >> 1;
        int tmul = KLEN / len;
        for (int bf = tid; bf < 512; bf += 256) {
            int j = bf & (half - 1);
            int p1 = ((bf & ~(half - 1)) << 1) | j;
            int p2 = p1 + half;
            int ti = j * tmul;
            float wr = twr[ti], wi = twi[ti];
            float ar = re[p2], ai = im[p2];
            float vr = ar * wr - ai * wi;
            float vi = ar * wi + ai * wr;
            float ur = re[p1], ui = im[p1];
            re[p1] = ur + vr; im[p1] = ui + vi;
            re[p2] = ur - vr; im[p2] = ui - vi;
        }
        __syncthreads();
    }

    // Unpack real parts of both spectra and write.
    // Re F_k = (Re Z_k + Re Z_{N-k})/2 ; Re G_k = (Im Z_k + Im Z_{N-k})/2
    size_t obase0 = (((size_t)b * NW + w) * NC + c0) * NBINS;
    size_t obase1 = obase0 + NBINS;
    for (int k = tid; k < NBINS; k += 256) {
        int rk = (KLEN - k) & (KLEN - 1);
        out[obase0 + k] = 0.5f * (re[k] + re[rk]);
        out[obase1 + k] = 0.5f * (im[k] + im[rk]);
    }
}

extern "C" void kernel_launch(void* const* d_in, const int* in_sizes, int n_in,
                              void* d_out, int out_size, void* d_ws, size_t ws_size,
                              hipStream_t stream) {
    const float* x = nullptr;
    const float* dlnf = nullptr;
    for (int i = 0; i < n_in; ++i) {
        if (in_sizes[i] == NB * NSAMP)      x = (const float*)d_in[i];
        else if (in_sizes[i] == NC)         dlnf = (const float*)d_in[i];
    }
    if (!x)    x    = (const float*)d_in[0];
    if (!dlnf) dlnf = (const float*)d_in[1];
    float* out = (float*)d_out;

    int*   lo_t = (int*)d_ws;
    float* fr_t = (float*)((char*)d_ws + MAPN * sizeof(int));
    float* ja_t = (float*)((char*)d_ws + MAPN * (sizeof(int) + sizeof(float)));

    warpmap_kernel<<<NC, 256, 0, stream>>>(dlnf, lo_t, fr_t, ja_t);

    const int nblocks = NB * NW * (NC / 2);  // 16352
    dechirp_fft2_kernel<<<nblocks, 256, 0, stream>>>(x, lo_t, fr_t, ja_t, out);
}

// Round 20
// 90.103 us; speedup vs baseline: 44.3727x; 2.1144x over previous
//
#include <hip/hip_runtime.h>

#define KLEN 1024
#define HOP 512
#define NW 511
#define NB 4
#define NC 16
#define NBINS 513
#define NSAMP 262144
#define MAPN (NC * KLEN)

// ws layout (bytes):
//   lo_t  int[MAPN]      @ 0
//   fr_t  float[MAPN]    @ 65536
//   ja_t  float[MAPN]    @ 131072
//   twr   float[512]     @ 196608   (cos 2pi t/1024)
//   twi   float[512]     @ 198656   (-sin 2pi t/1024)
//   hann  float[1024]    @ 200704
#define WS_FR   65536
#define WS_JA   131072
#define WS_TWR  196608
#define WS_TWI  198656
#define WS_HANN 200704

#define PAD(i) ((i) + (((i) >> 5) << 2))   // 16B-aligned anti-conflict pad

__global__ __launch_bounds__(256) void warpmap_kernel(
    const float* __restrict__ dlnf,
    int* __restrict__ lo_t, float* __restrict__ fr_t, float* __restrict__ ja_t,
    float* __restrict__ g_twr, float* __restrict__ g_twi, float* __restrict__ g_hann)
{
    const int c = blockIdx.x;
    const double TWO_PI = 6.283185307179586476925287;
    const double beta = 2.0 * (double)dlnf[c];
    const bool small = fabs(beta) < 1e-8;
    const double bs = small ? 1e-8 : beta;
    const double e2b = exp(2.0 * bs);
    const double t_mid = small ? 0.0 : (log(1.0 + 0.5 * (e2b - 1.0)) / bs - 1.0);

    for (int j = threadIdx.x; j < KLEN; j += 256) {
        double tau = 2.0 * (double)j / 1024.0 - 1.0;
        double ts, jac;
        if (small) { ts = tau; jac = 1.0; }
        else {
            ts = log(1.0 + (tau + 1.0) * 0.5 * (e2b - 1.0)) / bs - 1.0;
            jac = exp(-bs * (ts - t_mid));
        }
        double idxf = 512.0 * (ts + 1.0);
        int lo = (int)idxf;
        lo = lo < 0 ? 0 : (lo > 1022 ? 1022 : lo);
        lo_t[c * KLEN + j] = lo;
        fr_t[c * KLEN + j] = (float)(idxf - (double)lo);
        ja_t[c * KLEN + j] = (float)jac;
    }

    if (c == 0) {
        for (int t = threadIdx.x; t < 512; t += 256) {
            double ang = TWO_PI * (double)t / 1024.0;
            g_twr[t] = (float)cos(ang);
            g_twi[t] = (float)(-sin(ang));
        }
        for (int k = threadIdx.x; k < KLEN; k += 256)
            g_hann[k] = (float)(0.5 * (1.0 - cos(TWO_PI * (double)k / 1024.0)));
    }
}

__global__ __launch_bounds__(256) void dechirp_fft4_kernel(
    const float* __restrict__ x,
    const int* __restrict__ lo_t, const float* __restrict__ fr_t,
    const float* __restrict__ ja_t,
    const float* __restrict__ g_twr, const float* __restrict__ g_twi,
    const float* __restrict__ g_hann,
    float* __restrict__ out)
{
    __shared__ float wd[KLEN];
    __shared__ float re[PAD(KLEN - 1) + 1], im[PAD(KLEN - 1) + 1];
    __shared__ float twr[512], twi[512];

    const int tid = threadIdx.x;
    const int blin = blockIdx.x;            // ((b*NW + w)*8 + q)
    const int q = blin & 7;
    const int w = (blin >> 3) % NW;
    const int b = blin / (8 * NW);
    const int c0 = 2 * q, c1 = 2 * q + 1;

    // Stage tables + windowed frame (no transcendentals)
    for (int t = tid; t < 512; t += 256) { twr[t] = g_twr[t]; twi[t] = g_twi[t]; }
    const float* xrow = x + (size_t)b * NSAMP + (size_t)w * HOP;
    for (int k = tid; k < KLEN; k += 256)
        wd[k] = xrow[k] * g_hann[k];
    __syncthreads();

    // Resample both chirps; pack z = f + i*g at bit-reversed (padded) slots
    const int* lo0 = lo_t + c0 * KLEN;  const float* fr0 = fr_t + c0 * KLEN;  const float* ja0 = ja_t + c0 * KLEN;
    const int* lo1 = lo_t + c1 * KLEN;  const float* fr1 = fr_t + c1 * KLEN;  const float* ja1 = ja_t + c1 * KLEN;
    for (int j = tid; j < KLEN; j += 256) {
        int   a0 = lo0[j];  float f0 = fr0[j];
        float vf = (wd[a0] * (1.0f - f0) + wd[a0 + 1] * f0) * ja0[j];
        int   a1 = lo1[j];  float f1 = fr1[j];
        float vg = (wd[a1] * (1.0f - f1) + wd[a1 + 1] * f1) * ja1[j];
        int r = (int)(__brev((unsigned)j) >> 22);
        re[PAD(r)] = vf;
        im[PAD(r)] = vg;
    }
    __syncthreads();

    // 5 fused double-stages (radix-2 pairs); disjoint 4-point groups per thread
    #pragma unroll
    for (int s = 0; s <= 8; s += 2) {
        const int h = 1 << s;
        const int j = tid & (h - 1);
        const int base = ((tid >> s) << (s + 2)) + j;
        const int i0 = PAD(base), i1 = PAD(base + h), i2 = PAD(base + 2 * h), i3 = PAD(base + 3 * h);
        const int tA  = j << (9 - s);
        const int tB0 = j << (8 - s);
        const int tB1 = (j + h) << (8 - s);

        float ar0 = re[i0], ai0 = im[i0];
        float ar1 = re[i1], ai1 = im[i1];
        float ar2 = re[i2], ai2 = im[i2];
        float ar3 = re[i3], ai3 = im[i3];

        float wAr = twr[tA], wAi = twi[tA];
        float v1r = ar1 * wAr - ai1 * wAi, v1i = ar1 * wAi + ai1 * wAr;
        float b0r = ar0 + v1r, b0i = ai0 + v1i;
        float b1r = ar0 - v1r, b1i = ai0 - v1i;
        float v3r = ar3 * wAr - ai3 * wAi, v3i = ar3 * wAi + ai3 * wAr;
        float b2r = ar2 + v3r, b2i = ai2 + v3i;
        float b3r = ar2 - v3r, b3i = ai2 - v3i;

        float wB0r = twr[tB0], wB0i = twi[tB0];
        float v2r = b2r * wB0r - b2i * wB0i, v2i = b2r * wB0i + b2i * wB0r;
        float wB1r = twr[tB1], wB1i = twi[tB1];
        float v3br = b3r * wB1r - b3i * wB1i, v3bi = b3r * wB1i + b3i * wB1r;

        re[i0] = b0r + v2r;  im[i0] = b0i + v2i;
        re[i2] = b0r - v2r;  im[i2] = b0i - v2i;
        re[i1] = b1r + v3br; im[i1] = b1i + v3bi;
        re[i3] = b1r - v3br; im[i3] = b1i - v3bi;
        __syncthreads();
    }

    // Unpack real parts: Re F_k = (Re Z_k + Re Z_{N-k})/2 ; Re G_k = (Im Z_k + Im Z_{N-k})/2
    size_t obase0 = (((size_t)b * NW + w) * NC + c0) * NBINS;
    size_t obase1 = obase0 + NBINS;
    for (int k = tid; k < NBINS; k += 256) {
        int rk = (KLEN - k) & (KLEN - 1);
        out[obase0 + k] = 0.5f * (re[PAD(k)] + re[PAD(rk)]);
        out[obase1 + k] = 0.5f * (im[PAD(k)] + im[PAD(rk)]);
    }
}

extern "C" void kernel_launch(void* const* d_in, const int* in_sizes, int n_in,
                              void* d_out, int out_size, void* d_ws, size_t ws_size,
                              hipStream_t stream) {
    const float* x = nullptr;
    const float* dlnf = nullptr;
    for (int i = 0; i < n_in; ++i) {
        if (in_sizes[i] == NB * NSAMP)      x = (const float*)d_in[i];
        else if (in_sizes[i] == NC)         dlnf = (const float*)d_in[i];
    }
    if (!x)    x    = (const float*)d_in[0];
    if (!dlnf) dlnf = (const float*)d_in[1];
    float* out = (float*)d_out;

    char* ws = (char*)d_ws;
    int*   lo_t   = (int*)ws;
    float* fr_t   = (float*)(ws + WS_FR);
    float* ja_t   = (float*)(ws + WS_JA);
    float* g_twr  = (float*)(ws + WS_TWR);
    float* g_twi  = (float*)(ws + WS_TWI);
    float* g_hann = (float*)(ws + WS_HANN);

    warpmap_kernel<<<NC, 256, 0, stream>>>(dlnf, lo_t, fr_t, ja_t, g_twr, g_twi, g_hann);

    const int nblocks = NB * NW * (NC / 2);  // 16352
    dechirp_fft4_kernel<<<nblocks, 256, 0, stream>>>(x, lo_t, fr_t, ja_t,
                                                     g_twr, g_twi, g_hann, out);
}